// Round 5
// baseline (382.840 us; speedup 1.0000x reference)
//
#include <hip/hip_runtime.h>

// MoE dispatch-index fill. NUM_EXPERTS=64, N=67108864.
// Output 0: m_out[N] (int32) -- expert id per slot for i < total, else m_in[i]
// Output 1: starts[64] (int32) -- exclusive cumsum of counts
//
// Single fused kernel (R3) + non-temporal int4 stores (write-once stream ->
// bypass L2) and 32 KiB per block (2048 blocks). Fill is store-BW-bound:
// floor = 256 MB at ~6.5 TB/s ~= 41 us; the rest of the headline dur is
// harness restore/poison traffic (~165 us fillBuffer + input restore).
//
// NOTE: __builtin_nontemporal_store requires a clang vector type, not HIP's
// int4 struct -> use ext_vector_type(4).

#define N_EXPERTS 64
#define BLOCK 256
#define V4_PER_THREAD 8
#define ELEMS_PER_BLOCK (BLOCK * 4 * V4_PER_THREAD)  // 32768

typedef int v4i __attribute__((ext_vector_type(4)));

// last j in [0,63] with s[j] <= i  (s[0]==0 <= i always; never reads s[64])
__device__ __forceinline__ int upper_bound_m1(const int* __restrict__ s, int i) {
    int e = 0;
#pragma unroll
    for (int step = 32; step >= 1; step >>= 1) {
        if (s[e + step] <= i) e += step;
    }
    return e;
}

__global__ __launch_bounds__(BLOCK) void moe_fused_kernel(
    const int* __restrict__ counts,
    const int* __restrict__ m_in,
    int* __restrict__ m_out,
    int* __restrict__ starts_out,
    int n) {
    __shared__ int s_starts[N_EXPERTS + 1];  // [64] = total
    int tid = threadIdx.x;

    if (tid < 64) {  // wave 0 exactly: full-wave shfl is safe
        int c = counts[tid];
        int x = c;
#pragma unroll
        for (int off = 1; off < 64; off <<= 1) {
            int y = __shfl_up(x, off, 64);
            if (tid >= off) x += y;
        }
        s_starts[tid] = x - c;
        if (tid == 63) s_starts[64] = x;  // total
        if (blockIdx.x == 0) starts_out[tid] = x - c;  // output 1
    }
    __syncthreads();

    int total = s_starts[64];
    if (total > n) total = n;
    if (total < 0) total = 0;

    int blockBase = blockIdx.x * ELEMS_PER_BLOCK;
    if (blockBase >= n) return;
    int blockEnd = blockBase + ELEMS_PER_BLOCK;
    bool fullBlock = (blockEnd <= n);
    if (!fullBlock) blockEnd = n;

    if (fullBlock && blockEnd <= total) {
        int eA = upper_bound_m1(s_starts, blockBase);
        int eB = upper_bound_m1(s_starts, blockEnd - 1);
        if (eA == eB) {
            // ---- fast path: whole block is one expert id; pure nt store stream
            v4i val = {eA, eA, eA, eA};
#pragma unroll
            for (int v = 0; v < V4_PER_THREAD; ++v) {
                int i0 = blockBase + (v * BLOCK + tid) * 4;
                __builtin_nontemporal_store(val, reinterpret_cast<v4i*>(m_out + i0));
            }
            return;
        }
    } else if (fullBlock && blockBase >= total) {
        // ---- pure passthrough: vector copy m_in -> m_out
#pragma unroll
        for (int v = 0; v < V4_PER_THREAD; ++v) {
            int i0 = blockBase + (v * BLOCK + tid) * 4;
            v4i inv = *reinterpret_cast<const v4i*>(m_in + i0);
            __builtin_nontemporal_store(inv, reinterpret_cast<v4i*>(m_out + i0));
        }
        return;
    }

    // ---- general path: boundary blocks (expert boundary, `total`, or n tail)
#pragma unroll
    for (int v = 0; v < V4_PER_THREAD; ++v) {
        int i0 = blockBase + (v * BLOCK + tid) * 4;
        if (i0 >= n) break;
        v4i outv;
        if (i0 + 3 < total) {
            int e0 = upper_bound_m1(s_starts, i0);
            int e3 = upper_bound_m1(s_starts, i0 + 3);
            if (e0 == e3) {
                outv = (v4i){e0, e0, e0, e0};
            } else {
                outv.x = e0;
                outv.y = upper_bound_m1(s_starts, i0 + 1);
                outv.z = upper_bound_m1(s_starts, i0 + 2);
                outv.w = e3;
            }
        } else if (i0 >= total) {
            outv = *reinterpret_cast<const v4i*>(m_in + i0);
        } else {
            int vals[4];
#pragma unroll
            for (int j = 0; j < 4; ++j) {
                int i = i0 + j;
                vals[j] = (i < total) ? upper_bound_m1(s_starts, i) : m_in[i];
            }
            outv.x = vals[0]; outv.y = vals[1]; outv.z = vals[2]; outv.w = vals[3];
        }
        *reinterpret_cast<v4i*>(m_out + i0) = outv;
    }
}

extern "C" void kernel_launch(void* const* d_in, const int* in_sizes, int n_in,
                              void* d_out, int out_size, void* d_ws, size_t ws_size,
                              hipStream_t stream) {
    const int* counts = (const int*)d_in[0];
    // d_in[1] = expert_start_loc (unused; reference recomputes starts)
    const int* m_in = (const int*)d_in[2];
    int n = in_sizes[2];                 // 67108864
    int* out = (int*)d_out;              // m_out[n] then starts[64]
    int* starts_out = out + n;

    int blocks = (n + ELEMS_PER_BLOCK - 1) / ELEMS_PER_BLOCK;  // 2048
    moe_fused_kernel<<<blocks, BLOCK, 0, stream>>>(counts, m_in, out, starts_out, n);
}